// Round 15
// baseline (81.264 us; speedup 1.0000x reference)
//
#include <hip/hip_runtime.h>

// Problem constants (from reference): B=4096, N_IN=64, N_OUT=64, M=4096.
#define BATCH 4096
#define NIN   64
#define NOUT  64
#define M_TOT (NIN * NOUT)

// ---------------------------------------------------------------------------
// Kernel 1: build WM from (aW, uW, tW). One thread per m = j*64 + k.
// Transposed layout: WT[(j*3 + q)*64 + k] = row q of matrix (j,k)
// (quad = (Rq0,Rq1,Rq2,tq)); bottom row [0,0,0,1] implicit. 192 KiB in d_ws.
// ---------------------------------------------------------------------------
__global__ __launch_bounds__(256) void build_wm_kernel(
    const float* __restrict__ aW, const float* __restrict__ uW,
    const float* __restrict__ tW, float4* __restrict__ WT) {
  int m = blockIdx.x * 256 + threadIdx.x;
  if (m >= M_TOT) return;
  int j = m >> 6, k = m & 63;

  float a  = aW[m];
  float ux = 1.f / (1.f + expf(-uW[3 * m + 0]));
  float uy = 1.f / (1.f + expf(-uW[3 * m + 1]));
  float uz = 1.f / (1.f + expf(-uW[3 * m + 2]));
  float inv = 1.f / sqrtf(ux * ux + uy * uy + uz * uz);
  ux *= inv; uy *= inv; uz *= inv;

  float sa = sinf(a), ca = cosf(a);
  float xx = ux * ux, yy = uy * uy, zz = uz * uz;
  float xy = ux * uy, xz = ux * uz, yz = uy * uz;

  float R00 = ca * (1.f - xx) + xx;
  float R01 = -sa * uz + ca * (-xy) + xy;
  float R02 =  sa * uy + ca * (-xz) + xz;
  float R10 =  sa * uz + ca * (-xy) + xy;
  float R11 = ca * (1.f - yy) + yy;
  float R12 = -sa * ux + ca * (-yz) + yz;
  float R20 = -sa * uy + ca * (-xz) + xz;
  float R21 =  sa * ux + ca * (-yz) + yz;
  float R22 = ca * (1.f - zz) + zz;

  float t0 = tW[3 * m + 0], t1 = tW[3 * m + 1], t2 = tW[3 * m + 2];

  WT[(j * 3 + 0) * 64 + k] = make_float4(R00, R01, R02, t0);
  WT[(j * 3 + 1) * 64 + k] = make_float4(R10, R11, R12, t1);
  WT[(j * 3 + 2) * 64 + k] = make_float4(R20, R21, R22, t2);
}

// ---------------------------------------------------------------------------
// Kernel 2: chain product. Block = 256 threads = 4 waves = 4 batch rows
// (b = 4*blk + wid); each wave runs the FULL 64-step chain for its b
// (no j-split -> no combine, reference-exact association).
// Round 15 diagnosis: the invariant ~40% stall was TA/L1 THROUGHPUT --
// 3x 1KiB lane-coalesced W loads per wave-j = 48 CU-cyc of L1 vs 58
// CU-cyc of VALU (83% ratio). Fix: W staged in LDS, SHARED by the 4
// b-waves (VMEM W traffic /4), consumed via ds_read_b128 (~36 LDS-cyc
// per wave-j, different pipe). Double-buffered 4-j chunks (24 KiB LDS),
// reg-staged (T14): write next chunk pre-compute, issue chunk+2 loads
// early -> latencies hide under the 928-cyc compute window, one barrier
// per chunk. I stays on the scalar path (64 B/wave-j broadcast, cheap).
// Spill tripwire: WRITE_SIZE must stay 16384 KB.
// ---------------------------------------------------------------------------

#define CMUL_ROW(x)                                                            \
  {                                                                            \
    float t0 = c[x*4+0]*A00 + c[x*4+1]*A10 + c[x*4+2]*A20 + c[x*4+3]*A30;      \
    float t1 = c[x*4+0]*A01 + c[x*4+1]*A11 + c[x*4+2]*A21 + c[x*4+3]*A31;      \
    float t2 = c[x*4+0]*A02 + c[x*4+1]*A12 + c[x*4+2]*A22 + c[x*4+3]*A32;      \
    float t3 = c[x*4+0]*A03 + c[x*4+1]*A13 + c[x*4+2]*A23 + c[x*4+3]*A33;      \
    c[x*4+0] = t0; c[x*4+1] = t1; c[x*4+2] = t2; c[x*4+3] = t3;                \
  }

__global__ __launch_bounds__(256) void chain_kernel(
    const float4* __restrict__ I4, const float4* __restrict__ WT,
    float4* __restrict__ O4) {
  const int t    = threadIdx.x;
  const int lane = t & 63;
  const int wid  = t >> 6;               // 0..3 -> which batch row
  const int b    = (int)blockIdx.x * 4 + wid;

  __shared__ float4 buf[2][768];         // 2 x (4 j x 192 float4) = 24 KiB

  // wave-uniform scalar I base -> s_load (64 B/wave-j broadcast)
  const int ioff = __builtin_amdgcn_readfirstlane(b * (NIN * 4));
  const float4* __restrict__ Ib = I4 + ioff;

  // staging registers (3 float4/thread = one 4-j chunk per block)
  float4 s0, s1, s2;

  // prologue: chunk0 -> buf[0]; issue chunk1 loads
  s0 = WT[t]; s1 = WT[t + 256]; s2 = WT[t + 512];
  buf[0][t] = s0; buf[0][t + 256] = s1; buf[0][t + 512] = s2;
  {
    const float4* src = WT + 768;
    s0 = src[t]; s1 = src[t + 256]; s2 = src[t + 512];
  }
  __syncthreads();

  float c[16];
#pragma unroll
  for (int i = 0; i < 16; i++) c[i] = (i == 0 || i == 5 || i == 10 || i == 15) ? 1.f : 0.f;

  for (int ch = 0; ch < 16; ++ch) {
    const int slot = ch & 1;

    if (ch < 15) {
      // write next chunk (loaded one iteration ago; vmcnt wait is covered)
      buf[slot ^ 1][t] = s0;
      buf[slot ^ 1][t + 256] = s1;
      buf[slot ^ 1][t + 512] = s2;
      if (ch < 14) {  // issue chunk ch+2 loads; land during this+next compute
        const float4* src = WT + (size_t)(ch + 2) * 768;
        s0 = src[t]; s1 = src[t + 256]; s2 = src[t + 512];
      }
    }

#pragma unroll
    for (int jj = 0; jj < 4; ++jj) {
      const float4* wrow = &buf[slot][jj * 192];
      float4 w0 = wrow[lane], w1 = wrow[64 + lane], w2 = wrow[128 + lane];
      const int j = ch * 4 + jj;
      float4 r0 = Ib[j * 4 + 0], r1 = Ib[j * 4 + 1];
      float4 r2 = Ib[j * 4 + 2], r3 = Ib[j * 4 + 3];

      float A00 = r0.x*w0.x + r0.y*w1.x + r0.z*w2.x;
      float A01 = r0.x*w0.y + r0.y*w1.y + r0.z*w2.y;
      float A02 = r0.x*w0.z + r0.y*w1.z + r0.z*w2.z;
      float A03 = r0.x*w0.w + r0.y*w1.w + r0.z*w2.w + r0.w;
      float A10 = r1.x*w0.x + r1.y*w1.x + r1.z*w2.x;
      float A11 = r1.x*w0.y + r1.y*w1.y + r1.z*w2.y;
      float A12 = r1.x*w0.z + r1.y*w1.z + r1.z*w2.z;
      float A13 = r1.x*w0.w + r1.y*w1.w + r1.z*w2.w + r1.w;
      float A20 = r2.x*w0.x + r2.y*w1.x + r2.z*w2.x;
      float A21 = r2.x*w0.y + r2.y*w1.y + r2.z*w2.y;
      float A22 = r2.x*w0.z + r2.y*w1.z + r2.z*w2.z;
      float A23 = r2.x*w0.w + r2.y*w1.w + r2.z*w2.w + r2.w;
      float A30 = r3.x*w0.x + r3.y*w1.x + r3.z*w2.x;
      float A31 = r3.x*w0.y + r3.y*w1.y + r3.z*w2.y;
      float A32 = r3.x*w0.z + r3.y*w1.z + r3.z*w2.z;
      float A33 = r3.x*w0.w + r3.y*w1.w + r3.z*w2.w + r3.w;

      CMUL_ROW(0) CMUL_ROW(1) CMUL_ROW(2) CMUL_ROW(3)
    }
    __syncthreads();
  }

  // store O[b][lane] (16 consecutive floats)
  float4* o = O4 + ((size_t)b * NOUT + lane) * 4;
  o[0] = make_float4(c[0],  c[1],  c[2],  c[3]);
  o[1] = make_float4(c[4],  c[5],  c[6],  c[7]);
  o[2] = make_float4(c[8],  c[9],  c[10], c[11]);
  o[3] = make_float4(c[12], c[13], c[14], c[15]);
}

extern "C" void kernel_launch(void* const* d_in, const int* in_sizes, int n_in,
                              void* d_out, int out_size, void* d_ws, size_t ws_size,
                              hipStream_t stream) {
  const float* I  = (const float*)d_in[0];
  const float* aW = (const float*)d_in[1];
  const float* uW = (const float*)d_in[2];
  const float* tW = (const float*)d_in[3];

  float4* WT = (float4*)d_ws;  // 192 KiB scratch for transposed WM

  build_wm_kernel<<<M_TOT / 256, 256, 0, stream>>>(aW, uW, tW, WT);
  chain_kernel<<<BATCH / 4, 256, 0, stream>>>((const float4*)I, WT, (float4*)d_out);
}